// Round 2
// baseline (350.815 us; speedup 1.0000x reference)
//
#include <hip/hip_runtime.h>
#include <hip/hip_bf16.h>
#include <type_traits>
#include <cstdint>

// Problem constants
#define IN_DIM   512
#define OUT_DIM  1024
#define RANKP    8
#define MROWS    32768    // 8 * 4096

typedef float f32x4 __attribute__((ext_vector_type(4)));
typedef short s8vec __attribute__((ext_vector_type(8)));
typedef __bf16 b8vec __attribute__((ext_vector_type(8)));

// Pick whichever operand vector type the gfx950 mfma builtin accepts
// (guide shows short8; clang may declare V8 __bf16). SFINAE resolves it.
template <typename V, typename = void>
struct mfma_ok : std::false_type {};
template <typename V>
struct mfma_ok<V, std::void_t<decltype(__builtin_amdgcn_mfma_f32_16x16x32_bf16(
    std::declval<V>(), std::declval<V>(), std::declval<f32x4>(), 0, 0, 0))>>
    : std::true_type {};
using frag_t = std::conditional_t<mfma_ok<s8vec>::value, s8vec, b8vec>;

// async global->LDS 16B copy (low 32 bits of a flat LDS pointer are the LDS
// offset on AMDGPU).
__device__ __forceinline__ void async_copy16(void* lds, const void* g) {
    __builtin_amdgcn_global_load_lds(
        (const __attribute__((address_space(1))) void*)(uintptr_t)g,
        (__attribute__((address_space(3))) void*)(uint32_t)(uintptr_t)lds,
        16, 0, 0);
}

// ---------------- K1: column partial sums of x + bf16 cast ----------------
// grid 256 x 256 threads; block b handles rows [128b, 128b+128)
__global__ void geo_k1_reduce_cast(const float* __restrict__ x,
                                   __hip_bfloat16* __restrict__ xh,
                                   float* __restrict__ partial) {
    const int tid = threadIdx.x;
    const int rb  = blockIdx.x;
    const int c0 = tid, c1 = tid + 256;
    float s0 = 0.f, s1 = 0.f;
    const int r0 = rb * 128;
    for (int r = r0; r < r0 + 128; ++r) {
        const size_t base = (size_t)r * IN_DIM;
        float v0 = x[base + c0];
        float v1 = x[base + c1];
        s0 += v0; s1 += v1;
        xh[base + c0] = __float2bfloat16(v0);
        xh[base + c1] = __float2bfloat16(v1);
    }
    partial[(size_t)rb * IN_DIM + c0] = s0;
    partial[(size_t)rb * IN_DIM + c1] = s1;
}

// ---------------- K2: all small algebra in one block ----------------
__device__ __forceinline__ void mm16(float (*D)[16], float (*A)[16], float (*B)[16]) {
    const int tid = threadIdx.x;
    const int i = tid >> 4, j = tid & 15;
    float s = 0.f;
    if (tid < 256) {
#pragma unroll
        for (int k = 0; k < 16; ++k) s += A[i][k] * B[k][j];
    }
    __syncthreads();
    if (tid < 256) D[i][j] = s;
    __syncthreads();
}

__global__ void geo_k2_small(const float* __restrict__ partial,
                             const float* __restrict__ Wa, const float* __restrict__ La,
                             const float* __restrict__ Ra, const float* __restrict__ Wb,
                             const float* __restrict__ Lb, const float* __restrict__ Rb,
                             float* __restrict__ Vws, float* __restrict__ Lbp,
                             float* __restrict__ RRws, float* __restrict__ Pi8ws) {
    __shared__ float zbar[IN_DIM];
    __shared__ float red[32][8];
    __shared__ float ab[8], bb[8];
    __shared__ float G16[16][16], Jm[16][16];
    __shared__ float C2m[16][16], C3m[16][16], C4m[16][16];
    __shared__ float Cp[16][16], Cq[16][16];
    __shared__ float Pi[16][16], Xi[16][16], T1[16][16], T2[16][16], Ct[16][16];
    __shared__ float Zm[8][16], Em[8][16];
    const int tid = threadIdx.x;  // 256

    // zbar = mean over all 32768 rows
    for (int c = tid; c < IN_DIM; c += 256) {
        float s = 0.f;
        for (int p = 0; p < 256; ++p) s += partial[(size_t)p * IN_DIM + c];
        zbar[c] = s * (1.0f / 32768.0f);
    }
    __syncthreads();

    // abar (threads 0..127), bbar (threads 128..255): zbar @ W
    {
        const int t = tid & 127, which = tid >> 7;
        const int r = t & 7, seg = t >> 3;  // 16 segments of 32
        const float* Wm = which ? Wb : Wa;
        float s = 0.f;
        for (int i = seg * 32; i < seg * 32 + 32; ++i) s += zbar[i] * Wm[i * 8 + r];
        red[seg + 16 * which][r] = s;
    }
    __syncthreads();
    if (tid < 16) {
        const int r = tid & 7, which = tid >> 3;
        float s = 0.f;
        for (int seg = 0; seg < 16; ++seg) s += red[seg + 16 * which][r];
        if (which) bb[r] = s; else ab[r] = s;
    }
    __syncthreads();

    // V = [abar.*La | Ra]  (512x16), Lbp = bbar.*Lb (512x8)
    for (int i = tid; i < IN_DIM; i += 256) {
#pragma unroll
        for (int r = 0; r < 8; ++r) {
            Vws[i * 16 + r]     = ab[r] * La[i * 8 + r];
            Vws[i * 16 + 8 + r] = Ra[i * 8 + r];
            Lbp[i * 8 + r]      = bb[r] * Lb[i * 8 + r];
        }
    }
    __syncthreads();

    // G16 = V^T V ; J
    {
        const int u = tid >> 4, v = tid & 15;
        float s = 0.f;
        for (int i = 0; i < IN_DIM; ++i) s += Vws[i * 16 + u] * Vws[i * 16 + v];
        G16[u][v] = s;
        float j = 0.f;
        if (u < 8 && v == u + 8) j = 1.f;
        if (u >= 8 && v == u - 8) j = -1.f;
        Jm[u][v] = j;
    }
    __syncthreads();

    // Core powers: C_{k+1} = C_k * G16 * J, C_1 = J
    mm16(T1, Jm, G16);  mm16(C2m, T1, Jm);
    mm16(T1, C2m, G16); mm16(C3m, T1, Jm);
    mm16(T1, C3m, G16); mm16(C4m, T1, Jm);

    const float h  = 0.125f;
    const float c1 = h, c2 = h * h * 0.5f, c3 = h * h * h * (1.f / 6.f), c4 = h * h * h * h * (1.f / 24.f);
    {
        const int i = tid >> 4, j = tid & 15;
        Cp[i][j] = c1 * Jm[i][j] + c2 * C2m[i][j] + c3 * C3m[i][j] + c4 * C4m[i][j];
        Cq[i][j] = c2 * Jm[i][j] + c3 * C2m[i][j] + c4 * C3m[i][j];
        Xi[i][j] = 0.f;
    }
    __syncthreads();
    {
        const int i = tid >> 4, j = tid & 15;
        Pi[i][j] = Cp[i][j];  // Pi_1
    }
    __syncthreads();

    // P^k = I + V Pi_k V^T ; Pi_{k+1} = Pi_k + Cp + Pi_k*G16*Cp ; Xi = sum_{k=1..7} Pi_k
    for (int it = 0; it < 7; ++it) {
        mm16(T1, Pi, G16);
        mm16(T2, T1, Cp);
        {
            const int i = tid >> 4, j = tid & 15;
            const float pij = Pi[i][j];
            Xi[i][j] += pij;
            Pi[i][j] = pij + Cp[i][j] + T2[i][j];
        }
        __syncthreads();
    }

    // Ct = 8*Cq + h*Xi + Cq*G16*Xi ;  write Pi8
    mm16(T1, Cq, G16);
    mm16(T2, T1, Xi);
    {
        const int i = tid >> 4, j = tid & 15;
        Ct[i][j] = 8.f * Cq[i][j] + h * Xi[i][j] + T2[i][j];
        Pi8ws[tid] = Pi[i][j];
    }
    __syncthreads();

    // Z = Rb^T V (8x16); E = Z*Ct (8x16)
    if (tid < 128) {
        const int r = tid >> 4, u = tid & 15;
        float s = 0.f;
        for (int j = 0; j < IN_DIM; ++j) s += Rb[j * 8 + r] * Vws[j * 16 + u];
        Zm[r][u] = s;
    }
    __syncthreads();
    if (tid < 128) {
        const int r = tid >> 4, u = tid & 15;
        float s = 0.f;
#pragma unroll
        for (int t = 0; t < 16; ++t) s += Zm[r][t] * Ct[t][u];
        Em[r][u] = s;
    }
    __syncthreads();

    // RR[r,j] = Rb[j,r] + sum_u E[r,u] V[j,u]   (8x512)
    for (int idx = tid; idx < 8 * IN_DIM; idx += 256) {
        const int r = idx >> 9, j = idx & 511;
        float s = Rb[j * 8 + r];
#pragma unroll
        for (int u = 0; u < 16; ++u) s += Em[r][u] * Vws[j * 16 + u];
        RRws[r * IN_DIM + j] = s;
    }
}

// ---------------- K3: YP = (U0 @ V) @ Pi8  [1024 x 16] ----------------
// one wave per row of U0
__global__ void geo_k3_yp(const float* __restrict__ U0, const float* __restrict__ Vws,
                          const float* __restrict__ Pi8, float* __restrict__ YP) {
    const int o = blockIdx.x;
    const int l = threadIdx.x;  // 64
    float p[16];
#pragma unroll
    for (int t = 0; t < 16; ++t) p[t] = 0.f;
    for (int kk = 0; kk < 8; ++kk) {
        const int k = l + kk * 64;
        const float u = U0[(size_t)o * IN_DIM + k];
#pragma unroll
        for (int t = 0; t < 16; ++t) p[t] += u * Vws[k * 16 + t];
    }
    for (int off = 32; off; off >>= 1) {
#pragma unroll
        for (int t = 0; t < 16; ++t) p[t] += __shfl_xor(p[t], off);
    }
    if (l < 16) {
        float s = 0.f;
#pragma unroll
        for (int t = 0; t < 16; ++t) s += p[t] * Pi8[t * 16 + l];
        YP[o * 16 + l] = s;
    }
}

// ---------------- K4: W = U0 + YP V^T + [0; Lbp RR] -> bf16 ----------------
// 1024 blocks x 512 threads
__global__ void geo_k4_buildw(const float* __restrict__ U0, const float* __restrict__ YP,
                              const float* __restrict__ Vws, const float* __restrict__ Lbp,
                              const float* __restrict__ RRws, __hip_bfloat16* __restrict__ wh) {
    const int o = blockIdx.x;
    const int j = threadIdx.x;
    float w = U0[(size_t)o * IN_DIM + j];
#pragma unroll
    for (int u = 0; u < 16; ++u) w += YP[o * 16 + u] * Vws[j * 16 + u];
    if (o >= IN_DIM) {
        const int op = o - IN_DIM;
#pragma unroll
        for (int r = 0; r < 8; ++r) w += Lbp[op * 8 + r] * RRws[r * IN_DIM + j];
    }
    wh[(size_t)o * IN_DIM + j] = __float2bfloat16(w);
}

// ---------------- K5: out = xh @ wh^T  (bf16 MFMA, fp32 out) ----------------
// 128x128 tile, BK=32, 256 threads (4 waves, each 64x64 via 4x4 16x16x32 MFMAs)
__global__ void __launch_bounds__(256) geo_k5_gemm(const __hip_bfloat16* __restrict__ A,
                                                   const __hip_bfloat16* __restrict__ B,
                                                   float* __restrict__ C) {
    __shared__ __hip_bfloat16 As[128 * 32];
    __shared__ __hip_bfloat16 Bs[128 * 32];
    const int tid  = threadIdx.x;
    const int m0   = blockIdx.x * 128;
    const int n0   = blockIdx.y * 128;
    const int lane = tid & 63;
    const int wave = tid >> 6;
    const int wm   = (wave >> 1) * 64;
    const int wn   = (wave & 1) * 64;

    // staging: thread t covers row t>>2, 8 elements at col (t&3)*8; each thread
    // does rows t>>2 and 64+(t>>2) -> LDS element offset = t*8 (contiguous 16B/lane)
    const int srow = tid >> 2;
    const int scol = (tid & 3) * 8;
    const __hip_bfloat16* gA0 = A + (size_t)(m0 + srow) * IN_DIM + scol;
    const __hip_bfloat16* gA1 = A + (size_t)(m0 + 64 + srow) * IN_DIM + scol;
    const __hip_bfloat16* gB0 = B + (size_t)(n0 + srow) * IN_DIM + scol;
    const __hip_bfloat16* gB1 = B + (size_t)(n0 + 64 + srow) * IN_DIM + scol;
    __hip_bfloat16* lA0 = As + (size_t)tid * 8;
    __hip_bfloat16* lA1 = As + (size_t)(tid + 256) * 8;
    __hip_bfloat16* lB0 = Bs + (size_t)tid * 8;
    __hip_bfloat16* lB1 = Bs + (size_t)(tid + 256) * 8;

    f32x4 acc[4][4];
#pragma unroll
    for (int t = 0; t < 4; ++t)
#pragma unroll
        for (int s = 0; s < 4; ++s) acc[t][s] = (f32x4){0.f, 0.f, 0.f, 0.f};

    // fragment base element offsets in LDS (A: m=lane&15, k=(lane>>4)*8+j)
    const int aoff = (wm + (lane & 15)) * 32 + (lane >> 4) * 8;
    const int boff = (wn + (lane & 15)) * 32 + (lane >> 4) * 8;

    for (int kt = 0; kt < 16; ++kt) {
        const int k0 = kt * 32;
        __syncthreads();
        async_copy16(lA0, gA0 + k0);
        async_copy16(lA1, gA1 + k0);
        async_copy16(lB0, gB0 + k0);
        async_copy16(lB1, gB1 + k0);
        __syncthreads();

        frag_t af[4], bfr[4];
#pragma unroll
        for (int t = 0; t < 4; ++t) af[t] = *(const frag_t*)(As + aoff + t * 16 * 32);
#pragma unroll
        for (int s = 0; s < 4; ++s) bfr[s] = *(const frag_t*)(Bs + boff + s * 16 * 32);
#pragma unroll
        for (int t = 0; t < 4; ++t)
#pragma unroll
            for (int s = 0; s < 4; ++s)
                acc[t][s] = __builtin_amdgcn_mfma_f32_16x16x32_bf16(af[t], bfr[s], acc[t][s], 0, 0, 0);
    }

    // C/D layout: col = lane&15, row = (lane>>4)*4 + v   [m89-verified]
    const int cm = m0 + wm + (lane >> 4) * 4;
    const int cn = n0 + wn + (lane & 15);
#pragma unroll
    for (int t = 0; t < 4; ++t)
#pragma unroll
        for (int s = 0; s < 4; ++s)
#pragma unroll
            for (int v = 0; v < 4; ++v)
                C[(size_t)(cm + t * 16 + v) * OUT_DIM + cn + s * 16] = acc[t][s][v];
}

extern "C" void kernel_launch(void* const* d_in, const int* in_sizes, int n_in,
                              void* d_out, int out_size, void* d_ws, size_t ws_size,
                              hipStream_t stream) {
    const float* x  = (const float*)d_in[0];
    const float* U0 = (const float*)d_in[1];
    const float* Wa = (const float*)d_in[2];
    const float* La = (const float*)d_in[3];
    const float* Ra = (const float*)d_in[4];
    const float* Wb = (const float*)d_in[5];
    const float* Lb = (const float*)d_in[6];
    const float* Rb = (const float*)d_in[7];
    float* out = (float*)d_out;

    char* ws = (char*)d_ws;
    __hip_bfloat16* xh   = (__hip_bfloat16*)(ws);                      // 33,554,432 B
    __hip_bfloat16* wh   = (__hip_bfloat16*)(ws + 33554432);           //  1,048,576 B
    float*          part = (float*)(ws + 34603008);                    //    524,288 B
    float*          Vws  = (float*)(ws + 35127296);                    //     32,768 B
    float*          Lbp  = (float*)(ws + 35160064);                    //     16,384 B
    float*          RRws = (float*)(ws + 35176448);                    //     16,384 B
    float*          Pi8  = (float*)(ws + 35192832);                    //      1,024 B
    float*          YP   = (float*)(ws + 35193856);                    //     65,536 B
    // total ws usage: ~35.3 MB

    geo_k1_reduce_cast<<<256, 256, 0, stream>>>(x, xh, part);
    geo_k2_small<<<1, 256, 0, stream>>>(part, Wa, La, Ra, Wb, Lb, Rb, Vws, Lbp, RRws, Pi8);
    geo_k3_yp<<<1024, 64, 0, stream>>>(U0, Vws, Pi8, YP);
    geo_k4_buildw<<<1024, 512, 0, stream>>>(U0, YP, Vws, Lbp, RRws, wh);
    geo_k5_gemm<<<dim3(256, 8), 256, 0, stream>>>(xh, wh, out);
}

// Round 3
// 311.987 us; speedup vs baseline: 1.1245x; 1.1245x over previous
//
#include <hip/hip_runtime.h>
#include <hip/hip_bf16.h>
#include <type_traits>
#include <cstdint>

// Problem constants
#define IN_DIM   512
#define OUT_DIM  1024
#define RANKP    8
#define MROWS    32768    // 8 * 4096

typedef float f32x4 __attribute__((ext_vector_type(4)));
typedef short s8vec __attribute__((ext_vector_type(8)));
typedef __bf16 b8vec __attribute__((ext_vector_type(8)));

template <typename V, typename = void>
struct mfma_ok : std::false_type {};
template <typename V>
struct mfma_ok<V, std::void_t<decltype(__builtin_amdgcn_mfma_f32_16x16x32_bf16(
    std::declval<V>(), std::declval<V>(), std::declval<f32x4>(), 0, 0, 0))>>
    : std::true_type {};
using frag_t = std::conditional_t<mfma_ok<s8vec>::value, s8vec, b8vec>;

__device__ __forceinline__ void async_copy16(void* lds, const void* g) {
    __builtin_amdgcn_global_load_lds(
        (const __attribute__((address_space(1))) void*)(uintptr_t)g,
        (__attribute__((address_space(3))) void*)(uint32_t)(uintptr_t)lds,
        16, 0, 0);
}

__device__ __forceinline__ unsigned short f2bf(float f) {
    unsigned int u = __float_as_uint(f);
    unsigned int r = (u + 0x7fffu + ((u >> 16) & 1u)) >> 16;
    return (unsigned short)r;
}

// ---------------- K1: bf16 cast + fused z@Wa / z@Wb partial (atomicAdd) -----
// grid 1024 x 256; block handles 32 rows. thread: 4 cols (float4), 16 rows.
__global__ void __launch_bounds__(256) geo_k1(const float* __restrict__ x,
                                              unsigned short* __restrict__ xh,
                                              const float* __restrict__ Wa,
                                              const float* __restrict__ Wb,
                                              float* __restrict__ gsum) {
    const int tid  = threadIdx.x;
    const int c4   = (tid & 127) * 4;
    const int half = tid >> 7;
    const int r0   = blockIdx.x * 32 + half * 16;
    float4 s = {0.f, 0.f, 0.f, 0.f};
    for (int i = 0; i < 16; ++i) {
        const size_t base = (size_t)(r0 + i) * IN_DIM + c4;
        float4 v = *(const float4*)(x + base);
        s.x += v.x; s.y += v.y; s.z += v.z; s.w += v.w;
        ushort4 h;
        h.x = f2bf(v.x); h.y = f2bf(v.y); h.z = f2bf(v.z); h.w = f2bf(v.w);
        *(ushort4*)(xh + base) = h;
    }
    // local 16-float projection: av[r] = sum_q s_q * Wa[c4+q][r]
    const float* wa = Wa + (size_t)c4 * 8;
    const float* wb = Wb + (size_t)c4 * 8;
    float av[8], bv[8];
#pragma unroll
    for (int r = 0; r < 8; ++r) {
        av[r] = s.x * wa[r] + s.y * wa[8 + r] + s.z * wa[16 + r] + s.w * wa[24 + r];
        bv[r] = s.x * wb[r] + s.y * wb[8 + r] + s.z * wb[16 + r] + s.w * wb[24 + r];
    }
#pragma unroll
    for (int off = 32; off; off >>= 1) {
#pragma unroll
        for (int r = 0; r < 8; ++r) {
            av[r] += __shfl_xor(av[r], off, 64);
            bv[r] += __shfl_xor(bv[r], off, 64);
        }
    }
    __shared__ float wred[4][16];
    const int lane = tid & 63, wave = tid >> 6;
    if (lane == 0) {
#pragma unroll
        for (int r = 0; r < 8; ++r) { wred[wave][r] = av[r]; wred[wave][8 + r] = bv[r]; }
    }
    __syncthreads();
    if (tid < 16) {
        float t = wred[0][tid] + wred[1][tid] + wred[2][tid] + wred[3][tid];
        atomicAdd(&gsum[tid], t);
    }
}

// ---------------- K2a: build V [512x16], Lbp [512x8] -----------------------
// grid 16 x 256; thread -> (row = b*32 + t>>3, r = t&7)
__global__ void geo_k2a(const float* __restrict__ gsum, const float* __restrict__ La,
                        const float* __restrict__ Ra, const float* __restrict__ Lb,
                        float* __restrict__ Vws, float* __restrict__ Lbp) {
    const int tid = threadIdx.x;
    const int i = blockIdx.x * 32 + (tid >> 3);
    const int r = tid & 7;
    const float sc = 1.0f / 32768.0f;
    const float ar = gsum[r] * sc;
    const float br = gsum[8 + r] * sc;
    Vws[i * 16 + r]     = ar * La[i * 8 + r];
    Vws[i * 16 + 8 + r] = Ra[i * 8 + r];
    Lbp[i * 8 + r]      = br * Lb[i * 8 + r];
}

// ---------------- K2b: G16 = V^T V (16x16), Z = Rb^T V (8x16), atomic ------
// grid 32 x 256; block handles 16 i-rows
__global__ void geo_k2b(const float* __restrict__ Vws, const float* __restrict__ Rb,
                        float* __restrict__ Gg, float* __restrict__ Zg) {
    __shared__ float sX[16][24];
    const int tid = threadIdx.x;
    const int i0 = blockIdx.x * 16;
    for (int e = tid; e < 384; e += 256) {
        const int row = e / 24, col = e - row * 24;
        sX[row][col] = (col < 16) ? Vws[(i0 + row) * 16 + col]
                                  : Rb[(i0 + row) * 8 + col - 16];
    }
    __syncthreads();
    {
        const int u = tid >> 4, v = tid & 15;
        float s = 0.f;
#pragma unroll
        for (int k = 0; k < 16; ++k) s += sX[k][u] * sX[k][v];
        atomicAdd(&Gg[tid], s);
    }
    if (tid < 128) {
        const int r = tid >> 4, u = tid & 15;
        float s = 0.f;
#pragma unroll
        for (int k = 0; k < 16; ++k) s += sX[k][16 + r] * sX[k][u];
        atomicAdd(&Zg[tid], s);
    }
}

// ---------------- K2c: 16x16 RK4 core chain + VP = V@Pi8 + RR --------------
__device__ __forceinline__ void mm16(float (*D)[16], float (*A)[16], float (*B)[16]) {
    const int tid = threadIdx.x;
    const int i = tid >> 4, j = tid & 15;
    float s = 0.f;
#pragma unroll
    for (int k = 0; k < 16; ++k) s += A[i][k] * B[k][j];
    __syncthreads();
    D[i][j] = s;
    __syncthreads();
}

__global__ void geo_k2c(const float* __restrict__ Gg, const float* __restrict__ Zg,
                        const float* __restrict__ Vws, const float* __restrict__ Rb,
                        float* __restrict__ VPws, float* __restrict__ RRws) {
    __shared__ float G16[16][16], Jm[16][16];
    __shared__ float C2m[16][16], C3m[16][16], C4m[16][16];
    __shared__ float Cp[16][16], Cq[16][16];
    __shared__ float Pi[16][16], Xi[16][16], T1[16][16], T2[16][16], Ct[16][16];
    __shared__ float Zm[8][16], Em[8][16];
    const int tid = threadIdx.x;  // 256
    const int i = tid >> 4, j = tid & 15;

    G16[i][j] = Gg[tid];
    float jm = 0.f;
    if (i < 8 && j == i + 8) jm = 1.f;
    if (i >= 8 && j == i - 8) jm = -1.f;
    Jm[i][j] = jm;
    if (tid < 128) Zm[tid >> 4][tid & 15] = Zg[tid];
    __syncthreads();

    // Core powers: C_{k+1} = C_k * G16 * J, C_1 = J
    mm16(T1, Jm, G16);  mm16(C2m, T1, Jm);
    mm16(T1, C2m, G16); mm16(C3m, T1, Jm);
    mm16(T1, C3m, G16); mm16(C4m, T1, Jm);

    const float h  = 0.125f;
    const float c1 = h, c2 = h * h * 0.5f, c3 = h * h * h * (1.f / 6.f),
                c4 = h * h * h * h * (1.f / 24.f);
    Cp[i][j] = c1 * Jm[i][j] + c2 * C2m[i][j] + c3 * C3m[i][j] + c4 * C4m[i][j];
    Cq[i][j] = c2 * Jm[i][j] + c3 * C2m[i][j] + c4 * C3m[i][j];
    Xi[i][j] = 0.f;
    __syncthreads();
    Pi[i][j] = Cp[i][j];  // Pi_1
    __syncthreads();

    // Pi_{k+1} = Pi_k + Cp + Pi_k*G16*Cp ; Xi = sum_{k=1..7} Pi_k
    for (int it = 0; it < 7; ++it) {
        mm16(T1, Pi, G16);
        mm16(T2, T1, Cp);
        const float pij = Pi[i][j];
        Xi[i][j] += pij;
        Pi[i][j] = pij + Cp[i][j] + T2[i][j];
        __syncthreads();
    }

    // Ct = 8*Cq + h*Xi + Cq*G16*Xi
    mm16(T1, Cq, G16);
    mm16(T2, T1, Xi);
    Ct[i][j] = 8.f * Cq[i][j] + h * Xi[i][j] + T2[i][j];
    __syncthreads();

    // Em = Zm * Ct (8x16)
    if (tid < 128) {
        const int r = tid >> 4, u = tid & 15;
        float s = 0.f;
#pragma unroll
        for (int t = 0; t < 16; ++t) s += Zm[r][t] * Ct[t][u];
        Em[r][u] = s;
    }
    __syncthreads();

    // VP = V @ Pi (512x16); RR[r][j] = Rb[j][r] + sum_u Em[r][u] V[j][u]
#pragma unroll
    for (int rr = 0; rr < 2; ++rr) {
        const int row = tid * 2 + rr;
        const float* vr = Vws + row * 16;
        float v[16];
#pragma unroll
        for (int q = 0; q < 4; ++q) {
            float4 t4 = *(const float4*)(vr + q * 4);
            v[q * 4] = t4.x; v[q * 4 + 1] = t4.y; v[q * 4 + 2] = t4.z; v[q * 4 + 3] = t4.w;
        }
#pragma unroll
        for (int u = 0; u < 16; ++u) {
            float s = 0.f;
#pragma unroll
            for (int k = 0; k < 16; ++k) s += v[k] * Pi[k][u];
            VPws[row * 16 + u] = s;
        }
#pragma unroll
        for (int r = 0; r < 8; ++r) {
            float s = Rb[row * 8 + r];
#pragma unroll
            for (int u = 0; u < 16; ++u) s += Em[r][u] * v[u];
            RRws[r * IN_DIM + row] = s;
        }
    }
}

// ---------------- K34: W row = U0 + (U0.VP) V^T + [0; Lbp RR] -> bf16 ------
// grid 1024 x 256; block per output row o; thread handles cols 2t, 2t+1
__global__ void __launch_bounds__(256) geo_k34(const float* __restrict__ U0,
                                               const float* __restrict__ Vws,
                                               const float* __restrict__ VPws,
                                               const float* __restrict__ Lbp,
                                               const float* __restrict__ RRws,
                                               unsigned short* __restrict__ wh) {
    const int o   = blockIdx.x;
    const int tid = threadIdx.x;
    const int j0  = tid * 2;
    const float2 u0 = *(const float2*)(U0 + (size_t)o * IN_DIM + j0);

    // partial YP[u] = sum_j U0[o][j] * VP[j][u]
    const float* vpa = VPws + j0 * 16;
    const float* vpb = vpa + 16;
    float p[16];
#pragma unroll
    for (int u = 0; u < 16; ++u) p[u] = u0.x * vpa[u] + u0.y * vpb[u];
#pragma unroll
    for (int off = 32; off; off >>= 1) {
#pragma unroll
        for (int u = 0; u < 16; ++u) p[u] += __shfl_xor(p[u], off, 64);
    }
    __shared__ float wred[4][16];
    __shared__ float sY[16];
    const int lane = tid & 63, wave = tid >> 6;
    if (lane == 0) {
#pragma unroll
        for (int u = 0; u < 16; ++u) wred[wave][u] = p[u];
    }
    __syncthreads();
    if (tid < 16) sY[tid] = wred[0][tid] + wred[1][tid] + wred[2][tid] + wred[3][tid];
    __syncthreads();

    const float* va = Vws + j0 * 16;
    const float* vb = va + 16;
    float w0 = u0.x, w1 = u0.y;
#pragma unroll
    for (int u = 0; u < 16; ++u) {
        const float s = sY[u];
        w0 += s * va[u];
        w1 += s * vb[u];
    }
    if (o >= IN_DIM) {
        const int op = o - IN_DIM;
#pragma unroll
        for (int r = 0; r < 8; ++r) {
            const float lb = Lbp[op * 8 + r];
            w0 += lb * RRws[r * IN_DIM + j0];
            w1 += lb * RRws[r * IN_DIM + j0 + 1];
        }
    }
    ushort2 hv;
    hv.x = f2bf(w0); hv.y = f2bf(w1);
    *(ushort2*)(wh + (size_t)o * IN_DIM + j0) = hv;
}

// ---------------- K5: out = xh @ wh^T  (bf16 MFMA, fp32 out) ----------------
__global__ void __launch_bounds__(256) geo_k5_gemm(const __hip_bfloat16* __restrict__ A,
                                                   const __hip_bfloat16* __restrict__ B,
                                                   float* __restrict__ C) {
    __shared__ __hip_bfloat16 As[128 * 32];
    __shared__ __hip_bfloat16 Bs[128 * 32];
    const int tid  = threadIdx.x;
    const int m0   = blockIdx.x * 128;
    const int n0   = blockIdx.y * 128;
    const int lane = tid & 63;
    const int wave = tid >> 6;
    const int wm   = (wave >> 1) * 64;
    const int wn   = (wave & 1) * 64;

    const int srow = tid >> 2;
    const int scol = (tid & 3) * 8;
    const __hip_bfloat16* gA0 = A + (size_t)(m0 + srow) * IN_DIM + scol;
    const __hip_bfloat16* gA1 = A + (size_t)(m0 + 64 + srow) * IN_DIM + scol;
    const __hip_bfloat16* gB0 = B + (size_t)(n0 + srow) * IN_DIM + scol;
    const __hip_bfloat16* gB1 = B + (size_t)(n0 + 64 + srow) * IN_DIM + scol;
    __hip_bfloat16* lA0 = As + (size_t)tid * 8;
    __hip_bfloat16* lA1 = As + (size_t)(tid + 256) * 8;
    __hip_bfloat16* lB0 = Bs + (size_t)tid * 8;
    __hip_bfloat16* lB1 = Bs + (size_t)(tid + 256) * 8;

    f32x4 acc[4][4];
#pragma unroll
    for (int t = 0; t < 4; ++t)
#pragma unroll
        for (int s = 0; s < 4; ++s) acc[t][s] = (f32x4){0.f, 0.f, 0.f, 0.f};

    const int aoff = (wm + (lane & 15)) * 32 + (lane >> 4) * 8;
    const int boff = (wn + (lane & 15)) * 32 + (lane >> 4) * 8;

    for (int kt = 0; kt < 16; ++kt) {
        const int k0 = kt * 32;
        __syncthreads();
        async_copy16(lA0, gA0 + k0);
        async_copy16(lA1, gA1 + k0);
        async_copy16(lB0, gB0 + k0);
        async_copy16(lB1, gB1 + k0);
        __syncthreads();

        frag_t af[4], bfr[4];
#pragma unroll
        for (int t = 0; t < 4; ++t) af[t] = *(const frag_t*)(As + aoff + t * 16 * 32);
#pragma unroll
        for (int s = 0; s < 4; ++s) bfr[s] = *(const frag_t*)(Bs + boff + s * 16 * 32);
#pragma unroll
        for (int t = 0; t < 4; ++t)
#pragma unroll
            for (int s = 0; s < 4; ++s)
                acc[t][s] = __builtin_amdgcn_mfma_f32_16x16x32_bf16(af[t], bfr[s], acc[t][s], 0, 0, 0);
    }

    const int cm = m0 + wm + (lane >> 4) * 4;
    const int cn = n0 + wn + (lane & 15);
#pragma unroll
    for (int t = 0; t < 4; ++t)
#pragma unroll
        for (int s = 0; s < 4; ++s)
#pragma unroll
            for (int v = 0; v < 4; ++v)
                C[(size_t)(cm + t * 16 + v) * OUT_DIM + cn + s * 16] = acc[t][s][v];
}

extern "C" void kernel_launch(void* const* d_in, const int* in_sizes, int n_in,
                              void* d_out, int out_size, void* d_ws, size_t ws_size,
                              hipStream_t stream) {
    const float* x  = (const float*)d_in[0];
    const float* U0 = (const float*)d_in[1];
    const float* Wa = (const float*)d_in[2];
    const float* La = (const float*)d_in[3];
    const float* Ra = (const float*)d_in[4];
    const float* Wb = (const float*)d_in[5];
    const float* Lb = (const float*)d_in[6];
    const float* Rb = (const float*)d_in[7];
    float* out = (float*)d_out;

    char* ws = (char*)d_ws;
    unsigned short* xh  = (unsigned short*)(ws);                 // 33,554,432 B
    unsigned short* wh  = (unsigned short*)(ws + 33554432);      //  1,048,576 B
    float* acc  = (float*)(ws + 34603008);                       //      2,048 B (zeroed)
    float* gsum = acc;                                           // 16 floats
    float* Gg   = acc + 16;                                      // 256 floats
    float* Zg   = acc + 272;                                     // 128 floats
    float* Vws  = (float*)(ws + 34605056);                       //     32,768 B
    float* Lbp  = (float*)(ws + 34637824);                       //     16,384 B
    float* RRws = (float*)(ws + 34654208);                       //     16,384 B
    float* VPws = (float*)(ws + 34670592);                       //     32,768 B

    hipMemsetAsync(acc, 0, 2048, stream);
    geo_k1<<<1024, 256, 0, stream>>>(x, xh, Wa, Wb, gsum);
    geo_k2a<<<16, 256, 0, stream>>>(gsum, La, Ra, Lb, Vws, Lbp);
    geo_k2b<<<32, 256, 0, stream>>>(Vws, Rb, Gg, Zg);
    geo_k2c<<<1, 256, 0, stream>>>(Gg, Zg, Vws, Rb, VPws, RRws);
    geo_k34<<<1024, 256, 0, stream>>>(U0, Vws, VPws, Lbp, RRws, wh);
    geo_k5_gemm<<<dim3(256, 8), 256, 0, stream>>>((const __hip_bfloat16*)xh,
                                                  (const __hip_bfloat16*)wh, out);
}

// Round 4
// 277.786 us; speedup vs baseline: 1.2629x; 1.1231x over previous
//
#include <hip/hip_runtime.h>
#include <hip/hip_bf16.h>
#include <type_traits>
#include <cstdint>

// Problem constants
#define IN_DIM   512
#define OUT_DIM  1024
#define MROWS    32768    // 8 * 4096

typedef float f32x4 __attribute__((ext_vector_type(4)));
typedef short s8vec __attribute__((ext_vector_type(8)));
typedef __bf16 b8vec __attribute__((ext_vector_type(8)));

template <typename V, typename = void>
struct mfma_ok : std::false_type {};
template <typename V>
struct mfma_ok<V, std::void_t<decltype(__builtin_amdgcn_mfma_f32_16x16x32_bf16(
    std::declval<V>(), std::declval<V>(), std::declval<f32x4>(), 0, 0, 0))>>
    : std::true_type {};
using frag_t = std::conditional_t<mfma_ok<s8vec>::value, s8vec, b8vec>;

__device__ __forceinline__ void async_copy16(void* lds, const void* g) {
    __builtin_amdgcn_global_load_lds(
        (const __attribute__((address_space(1))) void*)(uintptr_t)g,
        (__attribute__((address_space(3))) void*)(uint32_t)(uintptr_t)lds,
        16, 0, 0);
}

__device__ __forceinline__ unsigned short f2bf(float f) {
    unsigned int u = __float_as_uint(f);
    unsigned int r = (u + 0x7fffu + ((u >> 16) & 1u)) >> 16;
    return (unsigned short)r;
}

// ---------------- K1: bf16 cast + fused z@Wa / z@Wb per-block partials -----
// grid 1024 x 256; block handles 32 rows. thread: 4 cols (float4), 16 rows.
__global__ void __launch_bounds__(256) geo_k1(const float* __restrict__ x,
                                              unsigned short* __restrict__ xh,
                                              const float* __restrict__ Wa,
                                              const float* __restrict__ Wb,
                                              float* __restrict__ part) {
    const int tid  = threadIdx.x;
    const int c4   = (tid & 127) * 4;
    const int half = tid >> 7;
    const int r0   = blockIdx.x * 32 + half * 16;
    float4 s = {0.f, 0.f, 0.f, 0.f};
    for (int i = 0; i < 16; ++i) {
        const size_t base = (size_t)(r0 + i) * IN_DIM + c4;
        float4 v = *(const float4*)(x + base);
        s.x += v.x; s.y += v.y; s.z += v.z; s.w += v.w;
        ushort4 h;
        h.x = f2bf(v.x); h.y = f2bf(v.y); h.z = f2bf(v.z); h.w = f2bf(v.w);
        *(ushort4*)(xh + base) = h;
    }
    const float* wa = Wa + (size_t)c4 * 8;
    const float* wb = Wb + (size_t)c4 * 8;
    float av[8], bv[8];
#pragma unroll
    for (int r = 0; r < 8; ++r) {
        av[r] = s.x * wa[r] + s.y * wa[8 + r] + s.z * wa[16 + r] + s.w * wa[24 + r];
        bv[r] = s.x * wb[r] + s.y * wb[8 + r] + s.z * wb[16 + r] + s.w * wb[24 + r];
    }
#pragma unroll
    for (int off = 32; off; off >>= 1) {
#pragma unroll
        for (int r = 0; r < 8; ++r) {
            av[r] += __shfl_xor(av[r], off, 64);
            bv[r] += __shfl_xor(bv[r], off, 64);
        }
    }
    __shared__ float wred[4][16];
    const int lane = tid & 63, wave = tid >> 6;
    if (lane == 0) {
#pragma unroll
        for (int r = 0; r < 8; ++r) { wred[wave][r] = av[r]; wred[wave][8 + r] = bv[r]; }
    }
    __syncthreads();
    if (tid < 16)
        part[(size_t)blockIdx.x * 16 + tid] =
            wred[0][tid] + wred[1][tid] + wred[2][tid] + wred[3][tid];
}

// ---------------- K2: merged small algebra, 1 block, V in LDS --------------
__device__ __forceinline__ void mm16(float (*D)[16], float (*A)[16], float (*B)[16]) {
    const int tid = threadIdx.x;
    const int i = tid >> 4, j = tid & 15;
    float s = 0.f;
#pragma unroll
    for (int k = 0; k < 16; ++k) s += A[i][k] * B[k][j];
    __syncthreads();
    D[i][j] = s;
    __syncthreads();
}

__global__ void __launch_bounds__(256) geo_k2(const float* __restrict__ part,
                                              const float* __restrict__ La,
                                              const float* __restrict__ Ra,
                                              const float* __restrict__ Lb,
                                              const float* __restrict__ Rb,
                                              float* __restrict__ Vws,
                                              float* __restrict__ Lbp,
                                              float* __restrict__ VPws,
                                              float* __restrict__ RRws) {
    __shared__ float sV[IN_DIM][16];   // 32 KB
    __shared__ float sRb[IN_DIM][8];   // 16 KB
    __shared__ float red2[16][16];
    __shared__ float gs[16];
    __shared__ float G16[16][16], Jm[16][16];
    __shared__ float C2m[16][16], C3m[16][16], C4m[16][16];
    __shared__ float Cp[16][16], Cq[16][16];
    __shared__ float Pi[16][16], Xi[16][16], T1[16][16], T2[16][16], Ct[16][16];
    __shared__ float Zm[8][16], Em[8][16];
    const int tid = threadIdx.x;  // 256
    const int i = tid >> 4, j = tid & 15;

    // phase 0: reduce part[1024][16] -> gs (already scaled to the mean)
    {
        const int u = tid & 15, c = tid >> 4;  // 16 chunks x 64 rows
        float s = 0.f;
        for (int q = 0; q < 64; ++q) s += part[(size_t)(c * 64 + q) * 16 + u];
        red2[c][u] = s;
    }
    __syncthreads();
    if (tid < 16) {
        float s = 0.f;
#pragma unroll
        for (int c = 0; c < 16; ++c) s += red2[c][tid];
        gs[tid] = s * (1.0f / 32768.0f);
    }
    __syncthreads();

    // phase 1: build sV = [abar.*La | Ra], sRb, Lbp (global), Vws (global)
    for (int rr = 0; rr < 2; ++rr) {
        const int row = tid * 2 + rr;
#pragma unroll
        for (int r = 0; r < 8; ++r) {
            const float vl = gs[r] * La[row * 8 + r];
            const float vr = Ra[row * 8 + r];
            sV[row][r]     = vl;
            sV[row][8 + r] = vr;
            Vws[row * 16 + r]     = vl;
            Vws[row * 16 + 8 + r] = vr;
            sRb[row][r] = Rb[row * 8 + r];
            Lbp[row * 8 + r] = gs[8 + r] * Lb[row * 8 + r];
        }
    }
    __syncthreads();

    // phase 2: G16 = V^T V, Zm = Rb^T V (from LDS)
    {
        float s = 0.f;
        for (int k = 0; k < IN_DIM; ++k) s += sV[k][i] * sV[k][j];
        G16[i][j] = s;
        float jm = 0.f;
        if (i < 8 && j == i + 8) jm = 1.f;
        if (i >= 8 && j == i - 8) jm = -1.f;
        Jm[i][j] = jm;
    }
    if (tid < 128) {
        const int r = tid >> 4, u = tid & 15;
        float s = 0.f;
        for (int k = 0; k < IN_DIM; ++k) s += sRb[k][r] * sV[k][u];
        Zm[r][u] = s;
    }
    __syncthreads();

    // phase 3: RK4 core chain (16x16)
    mm16(T1, Jm, G16);  mm16(C2m, T1, Jm);
    mm16(T1, C2m, G16); mm16(C3m, T1, Jm);
    mm16(T1, C3m, G16); mm16(C4m, T1, Jm);

    const float h  = 0.125f;
    const float c1 = h, c2 = h * h * 0.5f, c3 = h * h * h * (1.f / 6.f),
                c4 = h * h * h * h * (1.f / 24.f);
    Cp[i][j] = c1 * Jm[i][j] + c2 * C2m[i][j] + c3 * C3m[i][j] + c4 * C4m[i][j];
    Cq[i][j] = c2 * Jm[i][j] + c3 * C2m[i][j] + c4 * C3m[i][j];
    Xi[i][j] = 0.f;
    __syncthreads();
    Pi[i][j] = Cp[i][j];
    __syncthreads();

    for (int it = 0; it < 7; ++it) {
        mm16(T1, Pi, G16);
        mm16(T2, T1, Cp);
        const float pij = Pi[i][j];
        Xi[i][j] += pij;
        Pi[i][j] = pij + Cp[i][j] + T2[i][j];
        __syncthreads();
    }

    mm16(T1, Cq, G16);
    mm16(T2, T1, Xi);
    Ct[i][j] = 8.f * Cq[i][j] + h * Xi[i][j] + T2[i][j];
    __syncthreads();

    // Em = Zm * Ct (8x16)
    if (tid < 128) {
        const int r = tid >> 4, u = tid & 15;
        float s = 0.f;
#pragma unroll
        for (int t = 0; t < 16; ++t) s += Zm[r][t] * Ct[t][u];
        Em[r][u] = s;
    }
    __syncthreads();

    // phase 4: VP = V @ Pi (512x16); RR[r][j] = Rb[j][r] + sum_u Em[r][u] V[j][u]
#pragma unroll
    for (int rr = 0; rr < 2; ++rr) {
        const int row = tid * 2 + rr;
        float v[16];
#pragma unroll
        for (int k = 0; k < 16; ++k) v[k] = sV[row][k];
#pragma unroll
        for (int u = 0; u < 16; ++u) {
            float s = 0.f;
#pragma unroll
            for (int k = 0; k < 16; ++k) s += v[k] * Pi[k][u];
            VPws[row * 16 + u] = s;
        }
#pragma unroll
        for (int r = 0; r < 8; ++r) {
            float s = sRb[row][r];
#pragma unroll
            for (int u = 0; u < 16; ++u) s += Em[r][u] * v[u];
            RRws[r * IN_DIM + row] = s;
        }
    }
}

// ---------------- K34: W row = U0 + (U0.VP) V^T + [0; Lbp RR] -> bf16 ------
__global__ void __launch_bounds__(256) geo_k34(const float* __restrict__ U0,
                                               const float* __restrict__ Vws,
                                               const float* __restrict__ VPws,
                                               const float* __restrict__ Lbp,
                                               const float* __restrict__ RRws,
                                               unsigned short* __restrict__ wh) {
    const int o   = blockIdx.x;
    const int tid = threadIdx.x;
    const int j0  = tid * 2;
    const float2 u0 = *(const float2*)(U0 + (size_t)o * IN_DIM + j0);

    const float* vpa = VPws + j0 * 16;
    const float* vpb = vpa + 16;
    float p[16];
#pragma unroll
    for (int u = 0; u < 16; ++u) p[u] = u0.x * vpa[u] + u0.y * vpb[u];
#pragma unroll
    for (int off = 32; off; off >>= 1) {
#pragma unroll
        for (int u = 0; u < 16; ++u) p[u] += __shfl_xor(p[u], off, 64);
    }
    __shared__ float wred[4][16];
    __shared__ float sY[16];
    const int lane = tid & 63, wave = tid >> 6;
    if (lane == 0) {
#pragma unroll
        for (int u = 0; u < 16; ++u) wred[wave][u] = p[u];
    }
    __syncthreads();
    if (tid < 16) sY[tid] = wred[0][tid] + wred[1][tid] + wred[2][tid] + wred[3][tid];
    __syncthreads();

    const float* va = Vws + j0 * 16;
    const float* vb = va + 16;
    float w0 = u0.x, w1 = u0.y;
#pragma unroll
    for (int u = 0; u < 16; ++u) {
        const float s = sY[u];
        w0 += s * va[u];
        w1 += s * vb[u];
    }
    if (o >= IN_DIM) {
        const int op = o - IN_DIM;
#pragma unroll
        for (int r = 0; r < 8; ++r) {
            const float lb = Lbp[op * 8 + r];
            w0 += lb * RRws[r * IN_DIM + j0];
            w1 += lb * RRws[r * IN_DIM + j0 + 1];
        }
    }
    ushort2 hv;
    hv.x = f2bf(w0); hv.y = f2bf(w1);
    *(ushort2*)(wh + (size_t)o * IN_DIM + j0) = hv;
}

// ---------------- K5: out = xh @ wh^T (bf16 MFMA, BK=64, swizzled) ---------
// 128x128 tile, BK=64 (8 k-iters), 256 threads, 4 waves x (4x4 MFMA of 16x16x32)
// Staging swizzle: LDS[row][c] holds global chunk c ^ (row&7) (16B chunks),
// applied on the GLOBAL address side so global_load_lds stays LDS-contiguous.
__global__ void __launch_bounds__(256) geo_k5_gemm(const __hip_bfloat16* __restrict__ A,
                                                   const __hip_bfloat16* __restrict__ B,
                                                   float* __restrict__ C) {
    __shared__ __hip_bfloat16 As[128 * 64];   // 16 KB
    __shared__ __hip_bfloat16 Bs[128 * 64];   // 16 KB
    const int tid  = threadIdx.x;
    const int m0   = blockIdx.x * 128;
    const int n0   = blockIdx.y * 128;
    const int lane = tid & 63;
    const int wave = tid >> 6;
    const int wm   = (wave >> 1) * 64;
    const int wn   = (wave & 1) * 64;

    // staging: copy j of wave w -> region ri = w*4+j = rows [ri*8, ri*8+8)
    // lane covers row ri*8 + (lane>>3), global col chunk (lane&7)^(lane>>3)
    const int rowoff = lane >> 3;
    const int gcol   = ((lane & 7) ^ rowoff) * 8;   // swizzled global col (elems)
    const __hip_bfloat16* gA[4];
    const __hip_bfloat16* gB[4];
    char* lA[4];
    char* lB[4];
#pragma unroll
    for (int j2 = 0; j2 < 4; ++j2) {
        const int ri  = wave * 4 + j2;
        const int row = ri * 8 + rowoff;
        gA[j2] = A + (size_t)(m0 + row) * IN_DIM + gcol;
        gB[j2] = B + (size_t)(n0 + row) * IN_DIM + gcol;
        lA[j2] = (char*)As + ri * 1024 + lane * 16;
        lB[j2] = (char*)Bs + ri * 1024 + lane * 16;
    }

    f32x4 acc[4][4];
#pragma unroll
    for (int t = 0; t < 4; ++t)
#pragma unroll
        for (int s = 0; s < 4; ++s) acc[t][s] = (f32x4){0.f, 0.f, 0.f, 0.f};

    // fragment LDS byte offsets: row = w? + t*16 + (lane&15);
    // chunk = (h*4 + (lane>>4)) ^ (row&7), row&7 == lane&7 here
    const int frow = lane & 15;
    const int fsw  = lane & 7;
    const int fk   = lane >> 4;

    for (int kt = 0; kt < 8; ++kt) {
        const int k0 = kt * 64;
        __syncthreads();
#pragma unroll
        for (int j2 = 0; j2 < 4; ++j2) {
            async_copy16(lA[j2], gA[j2] + k0);
            async_copy16(lB[j2], gB[j2] + k0);
        }
        __syncthreads();

#pragma unroll
        for (int h = 0; h < 2; ++h) {
            frag_t af[4], bfr[4];
#pragma unroll
            for (int t = 0; t < 4; ++t)
                af[t] = *(const frag_t*)((const char*)As +
                        (size_t)(wm + t * 16 + frow) * 128 + (((h * 4 + fk) ^ fsw) * 16));
#pragma unroll
            for (int s = 0; s < 4; ++s)
                bfr[s] = *(const frag_t*)((const char*)Bs +
                        (size_t)(wn + s * 16 + frow) * 128 + (((h * 4 + fk) ^ fsw) * 16));
#pragma unroll
            for (int t = 0; t < 4; ++t)
#pragma unroll
                for (int s = 0; s < 4; ++s)
                    acc[t][s] = __builtin_amdgcn_mfma_f32_16x16x32_bf16(af[t], bfr[s], acc[t][s], 0, 0, 0);
        }
    }

    // C/D layout: col = lane&15, row = (lane>>4)*4 + v   [m89-verified]
    const int cm = m0 + wm + (lane >> 4) * 4;
    const int cn = n0 + wn + (lane & 15);
#pragma unroll
    for (int t = 0; t < 4; ++t)
#pragma unroll
        for (int s = 0; s < 4; ++s)
#pragma unroll
            for (int v = 0; v < 4; ++v)
                C[(size_t)(cm + t * 16 + v) * OUT_DIM + cn + s * 16] = acc[t][s][v];
}

extern "C" void kernel_launch(void* const* d_in, const int* in_sizes, int n_in,
                              void* d_out, int out_size, void* d_ws, size_t ws_size,
                              hipStream_t stream) {
    const float* x  = (const float*)d_in[0];
    const float* U0 = (const float*)d_in[1];
    const float* Wa = (const float*)d_in[2];
    const float* La = (const float*)d_in[3];
    const float* Ra = (const float*)d_in[4];
    const float* Wb = (const float*)d_in[5];
    const float* Lb = (const float*)d_in[6];
    const float* Rb = (const float*)d_in[7];
    float* out = (float*)d_out;

    char* ws = (char*)d_ws;
    unsigned short* xh  = (unsigned short*)(ws);             // 33,554,432 B
    unsigned short* wh  = (unsigned short*)(ws + 33554432);  //  1,048,576 B
    float* part = (float*)(ws + 34603008);                   //     65,536 B
    float* Vws  = (float*)(ws + 34668544);                   //     32,768 B
    float* Lbp  = (float*)(ws + 34701312);                   //     16,384 B
    float* RRws = (float*)(ws + 34717696);                   //     16,384 B
    float* VPws = (float*)(ws + 34734080);                   //     32,768 B

    geo_k1<<<1024, 256, 0, stream>>>(x, xh, Wa, Wb, part);
    geo_k2<<<1, 256, 0, stream>>>(part, La, Ra, Lb, Rb, Vws, Lbp, VPws, RRws);
    geo_k34<<<1024, 256, 0, stream>>>(U0, Vws, VPws, Lbp, RRws, wh);
    geo_k5_gemm<<<dim3(256, 8), 256, 0, stream>>>((const __hip_bfloat16*)xh,
                                                  (const __hip_bfloat16*)wh, out);
}